// Round 1
// 316.329 us; speedup vs baseline: 1.0178x; 1.0178x over previous
//
#include <hip/hip_runtime.h>

// TMoE layer: y = SCALING * (softmax(x@route_w^T) gated low-rank mixture)
// Factorization: g[t, e*64+r] = route[t,e]*c[t,r]*SCALING;  y = g @ Bflat^T
//   Bflat[o][e*64+r] = B[e][o][r]
//
// R4: k1 rewritten barrier-free. Old k1 was latency-bound (1 block/CU, 64KB
// LDS, 64 barriers, MfmaUtil 2%, HBM 14%). x has zero reuse in this skinny
// GEMM ([32768,1024]x[1024,72]) and the A-fragment layout (row=lane&15,
// k=quad*8+j) is exactly a 32B contiguous per-lane load — so fragments are
// loaded straight from global (x from HBM, w1 from L2), no sX/sW, no
// barriers in the K loop. 32 tok/block, 4 waves = (2 token groups) x
// (2 K-halves), 1024 blocks = 4/CU, LDS 22.5KB, launch_bounds(256,4).
// conv_w1/conv_b/k2 unchanged (R0/R3-proven).

#define NTOK    32768
#define DIM     1024
#define NW1     80          // 64 c-rows + 8 router rows + 8 zero pad
#define GDIM    512         // E*R
#define OUTD    1024
#define SCALING 0.25f

typedef __bf16 bf16x8 __attribute__((ext_vector_type(8)));
typedef float  f32x4  __attribute__((ext_vector_type(4)));

static __device__ __forceinline__ unsigned short f2bf(float f) {
    union { float f; unsigned u; } v; v.f = f;
    unsigned r = v.u + 0x7FFFu + ((v.u >> 16) & 1u);   // RNE
    return (unsigned short)(r >> 16);
}

// ---------------- weight conversion (R0-proven) ----------------
__global__ __launch_bounds__(256) void conv_w1(const float* __restrict__ A,
                                               const float* __restrict__ Rw,
                                               unsigned short* __restrict__ w1) {
    int i = blockIdx.x * 256 + threadIdx.x;
    if (i >= NW1 * DIM) return;
    int row = i >> 10, col = i & (DIM - 1);
    float v = 0.0f;
    if (row < 64)      v = A[(row << 10) + col];
    else if (row < 72) v = Rw[((row - 64) << 10) + col];
    w1[i] = f2bf(v);
}

__global__ __launch_bounds__(256) void conv_b(const float* __restrict__ B,
                                              unsigned short* __restrict__ bc) {
    int i = blockIdx.x * 256 + threadIdx.x;     // i = o*512 + e*64 + r
    if (i >= OUTD * GDIM) return;
    int o = i >> 9, er = i & 511;
    int e = er >> 6, r = er & 63;
    bc[i] = f2bf(B[(e << 16) + (o << 6) + r]);  // B[e][o][r], strides 65536/64/1
}

// ---------------- k1: routing + compress + gate (R4: barrier-free) -------
// 32 tokens/block. wave = (tokgroup<<1)|khalf: wave's 16 tokens x 80 feats,
// K range [khalf*512, khalf*512+512). A/B fragments loaded directly from
// global each 32-k step: per lane 2x float4 (x, 32B contiguous) + 5x bf16x8
// (w1, L2-resident), then 5 MFMAs. No LDS, no barriers in the loop.
// Epilogue: partial accs -> cAll[2][32][84] f32, one barrier, softmax,
// one barrier, gated bf16 pack -> g.
__global__ __launch_bounds__(256, 4) void k1_route_compress(
        const float* __restrict__ x,
        const unsigned short* __restrict__ w1,
        unsigned short* __restrict__ g) {
    __shared__ float cAll[2][32][84];
    __shared__ float rL[32][8];

    const int tid  = threadIdx.x;
    const int wave = tid >> 6;
    const int lane = tid & 63;
    const int quad = lane >> 4;
    const int l16  = lane & 15;
    const int t0   = blockIdx.x << 5;          // 32 tokens/block

    const int tokw  = (wave >> 1) << 4;        // 0 or 16
    const int khalf = wave & 1;                // K-half this wave owns
    const int kb0   = khalf << 9;              // 0 or 512

    f32x4 acc[5];
#pragma unroll
    for (int n = 0; n < 5; ++n) acc[n] = (f32x4){0.f, 0.f, 0.f, 0.f};

    // per-lane bases matching the 16x16x32 A/B fragment layout
    const float* xp = x + (size_t)(t0 + tokw + l16) * DIM + kb0 + (quad << 3);
    const unsigned short* wp = w1 + (l16 << 10) + kb0 + (quad << 3);

#pragma unroll 4
    for (int kk = 0; kk < 512; kk += 32) {
        float4 a0 = *(const float4*)(xp + kk);
        float4 a1 = *(const float4*)(xp + kk + 4);
        bf16x8 bfr[5];
#pragma unroll
        for (int n = 0; n < 5; ++n)
            bfr[n] = *(const bf16x8*)(wp + (n << 14) + kk);   // n*16 rows * 1024
        bf16x8 af;
        af[0] = (__bf16)a0.x; af[1] = (__bf16)a0.y;
        af[2] = (__bf16)a0.z; af[3] = (__bf16)a0.w;
        af[4] = (__bf16)a1.x; af[5] = (__bf16)a1.y;
        af[6] = (__bf16)a1.z; af[7] = (__bf16)a1.w;
#pragma unroll
        for (int n = 0; n < 5; ++n)
            acc[n] = __builtin_amdgcn_mfma_f32_16x16x32_bf16(af, bfr[n], acc[n], 0, 0, 0);
    }

    // D layout: col = lane&15 (feature), row = quad*4 + reg (token)
#pragma unroll
    for (int n = 0; n < 5; ++n)
#pragma unroll
        for (int r = 0; r < 4; ++r)
            cAll[khalf][tokw + (quad << 2) + r][(n << 4) + l16] = acc[n][r];
    __syncthreads();

    if (tid < 32) {
        float lg[8]; float m = -1e30f;
#pragma unroll
        for (int e = 0; e < 8; ++e) {
            lg[e] = cAll[0][tid][64 + e] + cAll[1][tid][64 + e];
            m = fmaxf(m, lg[e]);
        }
        float s = 0.f;
#pragma unroll
        for (int e = 0; e < 8; ++e) { lg[e] = expf(lg[e] - m); s += lg[e]; }
        float inv = SCALING / s;
#pragma unroll
        for (int e = 0; e < 8; ++e) rL[tid][e] = lg[e] * inv;
    }
    __syncthreads();

    // g write: 32 tok x 512 = 2048 bf16x8 chunks, 8 per thread, coalesced
#pragma unroll
    for (int i = 0; i < 8; ++i) {
        int c  = tid + (i << 8);       // 0..2047
        int t  = c >> 6;               // token in block
        int cc = c & 63;               // 16B chunk within token row
        int e  = cc >> 3;
        int r0 = (cc & 7) << 3;
        float rt = rL[t][e];
        f32x4 x0 = *(const f32x4*)&cAll[0][t][r0];
        f32x4 x1 = *(const f32x4*)&cAll[0][t][r0 + 4];
        f32x4 y0 = *(const f32x4*)&cAll[1][t][r0];
        f32x4 y1 = *(const f32x4*)&cAll[1][t][r0 + 4];
        bf16x8 pk;
#pragma unroll
        for (int j = 0; j < 4; ++j) pk[j]     = (__bf16)(rt * (x0[j] + y0[j]));
#pragma unroll
        for (int j = 0; j < 4; ++j) pk[j + 4] = (__bf16)(rt * (x1[j] + y1[j]));
        *(bf16x8*)(g + (size_t)(t0 + t) * GDIM + (cc << 3)) = pk;
    }
}

// ---------------- k2: y = g @ Bflat^T (R3-proven, unchanged) ----------------
// 128x128 tile, 4 waves x (64x64 = 4x4 frags). KC=64 — stage 128x64 tiles
// (row stride 72 halfwords, 16B-aligned), 32 MFMAs per barrier pair.
__global__ __launch_bounds__(256) void k2_up(
        const unsigned short* __restrict__ g,
        const unsigned short* __restrict__ bc,
        float* __restrict__ y) {
    __shared__ unsigned short sA[128][72];
    __shared__ unsigned short sB[128][72];

    const int tid  = threadIdx.x;
    const int wave = tid >> 6;
    const int lane = tid & 63;
    const int quad = lane >> 4;
    const int l16  = lane & 15;

    const int m0 = (blockIdx.x & 255) << 7;
    const int n0 = (blockIdx.x >> 8) << 7;
    const int mo = (wave & 1) << 6;
    const int no = (wave >> 1) << 6;

    f32x4 acc[4][4];
#pragma unroll
    for (int i = 0; i < 4; ++i)
#pragma unroll
        for (int j = 0; j < 4; ++j) acc[i][j] = (f32x4){0.f, 0.f, 0.f, 0.f};

    for (int k0 = 0; k0 < GDIM; k0 += 64) {
#pragma unroll
        for (int i = 0; i < 4; ++i) {
            int idx = tid + (i << 8);    // 0..1023
            int row = idx >> 3;          // 0..127
            int kq  = idx & 7;           // 16B chunk within 64 halfwords
            *(uint4*)(&sA[row][kq << 3]) =
                *(const uint4*)(g + (size_t)(m0 + row) * GDIM + k0 + (kq << 3));
            *(uint4*)(&sB[row][kq << 3]) =
                *(const uint4*)(bc + (size_t)(n0 + row) * GDIM + k0 + (kq << 3));
        }
        __syncthreads();
#pragma unroll
        for (int kk = 0; kk < 2; ++kk) {
            bf16x8 af[4], bfr[4];
#pragma unroll
            for (int i = 0; i < 4; ++i)
                af[i] = *(const bf16x8*)(&sA[mo + (i << 4) + l16][(kk << 5) + (quad << 3)]);
#pragma unroll
            for (int j = 0; j < 4; ++j)
                bfr[j] = *(const bf16x8*)(&sB[no + (j << 4) + l16][(kk << 5) + (quad << 3)]);
#pragma unroll
            for (int i = 0; i < 4; ++i)
#pragma unroll
                for (int j = 0; j < 4; ++j)
                    acc[i][j] = __builtin_amdgcn_mfma_f32_16x16x32_bf16(af[i], bfr[j], acc[i][j], 0, 0, 0);
        }
        __syncthreads();
    }

#pragma unroll
    for (int i = 0; i < 4; ++i)
#pragma unroll
        for (int j = 0; j < 4; ++j)
#pragma unroll
            for (int r = 0; r < 4; ++r) {
                int row = m0 + mo + (i << 4) + (quad << 2) + r;
                int col = n0 + no + (j << 4) + l16;
                y[(size_t)row * OUTD + col] = acc[i][j][r];
            }
}

extern "C" void kernel_launch(void* const* d_in, const int* in_sizes, int n_in,
                              void* d_out, int out_size, void* d_ws, size_t ws_size,
                              hipStream_t stream) {
    const float* x  = (const float*)d_in[0];   // [8,4096,1024]
    const float* rw = (const float*)d_in[1];   // [8,1024]
    const float* A  = (const float*)d_in[2];   // [64,1024]
    const float* B  = (const float*)d_in[3];   // [8,1024,64]
    float* y = (float*)d_out;                  // [8,4096,1024] fp32

    unsigned short* g  = (unsigned short*)d_ws;          // [32768][512] bf16
    unsigned short* w1 = g + (size_t)NTOK * GDIM;        // [80][1024] bf16
    unsigned short* bc = w1 + NW1 * DIM;                 // [1024][512] bf16

    conv_w1<<<(NW1 * DIM + 255) / 256, 256, 0, stream>>>(A, rw, w1);
    conv_b<<<(OUTD * GDIM + 255) / 256, 256, 0, stream>>>(B, bc);
    k1_route_compress<<<NTOK / 32, 256, 0, stream>>>(x, w1, g);
    k2_up<<<(NTOK / 128) * (OUTD / 128), 256, 0, stream>>>(g, bc, y);
}